// Round 2
// baseline (153.680 us; speedup 1.0000x reference)
//
#include <hip/hip_runtime.h>

// PS_L20_LSTM — r14: occupancy attack. Theory: r12/r13 ran at ONE 16-wave
// block/CU because total regs (arch VGPR + hidden AGPR accumulators) ~88/wave
// capped the CU at 20 waves — a second 16-wave block couldn't fit. Fix:
// (a) h-first restructure: materialize all 128 h-values into 4x half8 regs
//     (16 VGPR), then head runs NT=0..7 with a SINGLE 4-reg accumulator
//     (was 8 accs = 32 regs live through the whole half-pass);
// (b) gate phase consumes each 3-MFMA group with act4 immediately (12 live
//     f32 MFMA results instead of 24);
// (c) __launch_bounds__(1024, 8) forces the <=64-reg budget -> 2 blocks/CU.
// Math, MFMA count, LDS layout, staging identical to r13.

typedef _Float16 half8v  __attribute__((ext_vector_type(8)));
typedef _Float16 half4v  __attribute__((ext_vector_type(4)));
typedef float    float4v __attribute__((ext_vector_type(4)));

#define N_SZ   2048
#define BLOCKT 1024
#define NWAVES 16
#define NBLK   512          // 512 blk x 16 waves x 32 rows = 262144
#define WROWS  32

__device__ __forceinline__ float fast_rcp(float x) { return __builtin_amdgcn_rcpf(x); }
__device__ __forceinline__ float fast_exp2(float x) {
#if __has_builtin(__builtin_amdgcn_exp2f)
    return __builtin_amdgcn_exp2f(x);
#else
    return exp2f(x);
#endif
}

// Gate pre-activations arrive log2-scaled from the staged weights:
//   di = -log2e*i  -> u = 2^di        = e^-i
//   dg = 2log2e*g  -> v = 2^min(dg,C) = e^2g   (clamp: keep v-1 finite)
//   dv = -log2e*o  -> w = 2^min(dv,C) = e^-o   (clamp: keep 1+w finite)
// c = sigmoid(i)*tanh(g) = (v-1)/((1+u)(1+v));  h = sigmoid(o)*tanh(c).
// One rcp: r = 1/((1+u)(1+v)(1+w)); nm=(v-1)*r; c=nm*(1+w); h=nm*P(c^2).
// If any factor overflows to inf: r->0 -> nm->0 -> h=0 = correct limit.
__device__ __forceinline__ half4v act4(float4v di, float4v dg, float4v dv) {
    half4v h;
    #pragma unroll
    for (int j = 0; j < 4; ++j) {
        const float u  = fast_exp2(di[j]);
        const float v  = fast_exp2(fminf(dg[j], 115.0f));
        const float w  = fast_exp2(fminf(dv[j], 115.0f));
        const float a3 = 1.0f + w;
        const float r  = fast_rcp((1.0f + u) * (1.0f + v) * a3);
        const float nm = (v - 1.0f) * r;
        const float cv = nm * a3;
        const float t  = cv * cv;
        const float P  = __builtin_fmaf(t, __builtin_fmaf(t, __builtin_fmaf(t,
                         -0.02714f, 0.12052f), -0.33157f), 0.99986f);
        h[j] = (_Float16)(nm * P);
    }
    return h;
}

__global__ __launch_bounds__(BLOCKT, 8)   // 8 waves/SIMD -> 2 blocks/CU
void ps_lstm_r14(const float* __restrict__ x_,
                 const float* __restrict__ x1_,
                 const float* __restrict__ x2_,
                 const float* __restrict__ z1_,
                 const float* __restrict__ z2_,
                 const float* __restrict__ x1E_,
                 const float* __restrict__ x2E_,
                 const float* __restrict__ z1E_,
                 const float* __restrict__ z2E_,
                 const float* __restrict__ muB_,
                 const float* __restrict__ lb_,
                 const float* __restrict__ ub_,
                 const float* __restrict__ Wih_,   // [512][15]
                 const float* __restrict__ bih_,   // [512]
                 const float* __restrict__ bhh_,   // [512]
                 const float* __restrict__ W1_,    // [128][128]
                 const float* __restrict__ b1_,    // [128]
                 const float* __restrict__ W2_,    // [128]
                 const float* __restrict__ b2_,    // [1]
                 float* __restrict__ out_)         // [128][5*2048]
{
    // fragWih[g][kk][lane]: A[m=kk*16+(l&15)][k=(l>>4)*4+j], k==15 = fused bias,
    // pre-scaled by gate's log2 factor.                       6144 h = 12 KiB
    __shared__ __align__(16) _Float16 fragWih[3 * 8 * 64 * 4];
    // fragW1[nt][t][lane]: half8 B-frag for 16x16x32; element j holds
    // W1[n2=nt*16+(l&15)][k], k = 32t + (j<4 ? (l>>4)*4+j : 16+(l>>4)*4+j-4)
    // -- the exact neuron order the gate D-frags deliver.    16384 h = 32 KiB
    __shared__ __align__(16) _Float16 fragW1 [8 * 4 * 64 * 8];
    __shared__ __align__(16) _Float16 sFeat[NWAVES][WROWS * 16]; // 16 KiB
    __shared__ __align__(8)  float    sHead[2 * 128];  // (b1,W2) pairs, 1 KiB
    // total ~61 KiB -> 2 blocks/CU by LDS

    const int tid  = threadIdx.x;
    const int lane = tid & 63;
    const int w    = tid >> 6;
    const int c    = lane & 15;    // MFMA lane index
    const int q    = lane >> 4;    // quad

    // ---------- one-time staging ----------
    // gate weights, log2-domain pre-scale folded in (i,g,o; dead f skipped)
    for (int ch = tid; ch < 3 * 8 * 64; ch += BLOCKT) {      // 2 iters
        const int g   = ch >> 9;            // 0:i 1:g 2:o
        const int rem = ch & 511;
        const int kk  = rem >> 6;
        const int l   = rem & 63;
        const int m   = kk * 16 + (l & 15);
        const int q4  = l >> 4;
        const int grow = (g == 0 ? m : (g == 1 ? 256 + m : 384 + m));
        const float gs = (g == 1) ? 2.8853901f : -1.4426950f;  // ±log2e, 2log2e
        half4v hh;
        #pragma unroll
        for (int j = 0; j < 4; ++j) {
            const int k = q4 * 4 + j;
            const float raw = (k < 15) ? Wih_[grow * 15 + k]
                                       : (bih_[grow] + bhh_[grow]);
            hh[j] = (_Float16)(gs * raw);
        }
        *(half4v*)&fragWih[(size_t)ch * 4] = hh;
    }
    // W1^T frags in the paired-slice neuron order (j<4: slice 2t, j>=4: 2t+1)
    for (int ch = tid; ch < 8 * 4 * 64; ch += BLOCKT) {      // 2 iters
        const int nt = ch >> 8;
        const int t  = (ch >> 6) & 3;
        const int l  = ch & 63;
        const int n2 = nt * 16 + (l & 15);
        const int q4 = l >> 4;
        const int k0 = 32 * t + q4 * 4;          // j = 0..3
        const int k1 = k0 + 16;                  // j = 4..7
        const float4 a = *(const float4*)&W1_[n2 * 128 + k0];
        const float4 b = *(const float4*)&W1_[n2 * 128 + k1];
        half8v hh;
        hh[0] = (_Float16)a.x; hh[1] = (_Float16)a.y;
        hh[2] = (_Float16)a.z; hh[3] = (_Float16)a.w;
        hh[4] = (_Float16)b.x; hh[5] = (_Float16)b.y;
        hh[6] = (_Float16)b.z; hh[7] = (_Float16)b.w;
        *(half8v*)&fragW1[(size_t)ch * 8] = hh;
    }
    // head bias/weight pairs -> LDS (persistent VGPR relief)
    if (tid < 128) {
        sHead[2 * tid]     = b1_[tid];
        sHead[2 * tid + 1] = W2_[tid];
    }
    const float b2v = b2_[0];   // uniform -> SGPR

    __syncthreads();   // the only barrier

    const int rbase = (blockIdx.x * NWAVES + w) * WROWS;

    // ---------- stage 1: features (lanes 0..31, lane = row) ----------
    float ex = 0.f, ez1 = 0.f, ez2 = 0.f, eD1 = 0.f, eD2 = 0.f, elb = 0.f, eub = 0.f;
    if (lane < WROWS) {
        const int r = rbase + lane;
        const float x   = x_[r];
        const float x1  = x1_[r];
        const float x2  = x2_[r];
        float       z1  = z1_[r];
        float       z2  = z2_[r];
        const float x1E = x1E_[r];
        const float x2E = x2E_[r];
        const float z1E = z1E_[r];
        const float z2E = z2E_[r];
        const float mu  = muB_[r >> 11];

        z1 = ((z1 + mu) <= 0.0f) ? 0.0f : z1;
        z2 = ((z2 + mu) <= 0.0f) ? 0.0f : z2;
        float invD1 = (z1 + mu) * fast_rcp(x1 + mu + 1e-12f);
        float invD2 = (z2 + mu) * fast_rcp(x2 + mu + 1e-12f);
        invD1 = fminf(fmaxf(invD1, 0.0f), 100.0f);
        invD2 = fminf(fmaxf(invD2, 0.0f), 100.0f);

        const float f[15] = { x, x1, x2, z1, z2, x, z1, z2,
                              x1E, x2E, z1E, z2E, mu, invD1, invD2 };
        half8v f0, f1;
        #pragma unroll
        for (int k = 0; k < 8; ++k) f0[k] = (_Float16)f[k];
        #pragma unroll
        for (int k = 0; k < 7; ++k) f1[k] = (_Float16)f[8 + k];
        f1[7] = (_Float16)1.0f;                 // bias activator (k=15)
        *(half8v*)&sFeat[w][lane * 16]     = f0;
        *(half8v*)&sFeat[w][lane * 16 + 8] = f1;

        ex = x; ez1 = z1; ez2 = z2; eD1 = invD1; eD2 = invD2;
        elb = lb_[r]; eub = ub_[r];
    }
    // wave-private LDS; same-wave DS ordering -> no barrier

    float pr0 = 0.f, pr1 = 0.f;   // routed p for rows lane<16 / lane>=16

    // ---------- two 16-row half-passes ----------
    #pragma unroll 1
    for (int rh = 0; rh < 2; ++rh) {
        // feat B-frag: B[k=q*4+j][n=row c] (K=16 exactly)
        const half4v fB = *(const half4v*)&sFeat[w][(rh * 16 + c) * 16 + q * 4];

        // ----- gate phase: all 128 h-values -> 4x half8 regs (16 VGPR) -----
        // per slice-pair: 3 MFMA -> act4 -> 3 MFMA -> act4 (12 live f32 max)
        half8v h0, h1, h2, h3;
#define GSTEP(T, HOUT) { \
        const _Float16* wp = fragWih + lane * 4 + (T) * 512; \
        const float4v zc = {0.f, 0.f, 0.f, 0.f}; \
        const half4v Ai0 = *(const half4v*)(wp); \
        const half4v Ag0 = *(const half4v*)(wp + 2048); \
        const half4v Ao0 = *(const half4v*)(wp + 4096); \
        const float4v di0 = __builtin_amdgcn_mfma_f32_16x16x16f16(Ai0, fB, zc, 0, 0, 0); \
        const float4v dg0 = __builtin_amdgcn_mfma_f32_16x16x16f16(Ag0, fB, zc, 0, 0, 0); \
        const float4v dv0 = __builtin_amdgcn_mfma_f32_16x16x16f16(Ao0, fB, zc, 0, 0, 0); \
        const half4v hLo = act4(di0, dg0, dv0); \
        const half4v Ai1 = *(const half4v*)(wp + 256); \
        const half4v Ag1 = *(const half4v*)(wp + 2048 + 256); \
        const half4v Ao1 = *(const half4v*)(wp + 4096 + 256); \
        const float4v di1 = __builtin_amdgcn_mfma_f32_16x16x16f16(Ai1, fB, zc, 0, 0, 0); \
        const float4v dg1 = __builtin_amdgcn_mfma_f32_16x16x16f16(Ag1, fB, zc, 0, 0, 0); \
        const float4v dv1 = __builtin_amdgcn_mfma_f32_16x16x16f16(Ao1, fB, zc, 0, 0, 0); \
        const half4v hHi = act4(di1, dg1, dv1); \
        HOUT[0] = hLo[0]; HOUT[1] = hLo[1]; HOUT[2] = hLo[2]; HOUT[3] = hLo[3]; \
        HOUT[4] = hHi[0]; HOUT[5] = hHi[1]; HOUT[6] = hHi[2]; HOUT[7] = hHi[3]; }
        GSTEP(0, h0)  GSTEP(1, h1)  GSTEP(2, h2)  GSTEP(3, h3)
#undef GSTEP

        // ----- head phase: one 4-reg accumulator, NT sequential -----
        float p0 = 0.f, p1 = 0.f, p2 = 0.f, p3 = 0.f;
        #pragma unroll 1
        for (int nt = 0; nt < 8; ++nt) {
            const _Float16* w1p = fragW1 + lane * 8 + nt * 2048;
            const float4v zc = {0.f, 0.f, 0.f, 0.f};
            float4v acc;
            acc = __builtin_amdgcn_mfma_f32_16x16x32_f16(h0, *(const half8v*)(w1p       ), zc,  0, 0, 0);
            acc = __builtin_amdgcn_mfma_f32_16x16x32_f16(h1, *(const half8v*)(w1p +  512), acc, 0, 0, 0);
            acc = __builtin_amdgcn_mfma_f32_16x16x32_f16(h2, *(const half8v*)(w1p + 1024), acc, 0, 0, 0);
            acc = __builtin_amdgcn_mfma_f32_16x16x32_f16(h3, *(const half8v*)(w1p + 1536), acc, 0, 0, 0);
            const float2 bw = *(const float2*)(sHead + 2 * c + nt * 32);
            p0 = __builtin_fmaf(fmaxf(acc[0] + bw.x, 0.f), bw.y, p0);
            p1 = __builtin_fmaf(fmaxf(acc[1] + bw.x, 0.f), bw.y, p1);
            p2 = __builtin_fmaf(fmaxf(acc[2] + bw.x, 0.f), bw.y, p2);
            p3 = __builtin_fmaf(fmaxf(acc[3] + bw.x, 0.f), bw.y, p3);
        }

        // ----- reduce over c-lanes -> p per row, route to row-lane -----
        #pragma unroll
        for (int s = 1; s <= 8; s <<= 1) {
            p0 += __shfl_xor(p0, s, 64);
            p1 += __shfl_xor(p1, s, 64);
            p2 += __shfl_xor(p2, s, 64);
            p3 += __shfl_xor(p3, s, 64);
        }
        // all 16 c-lanes of quad q hold p_j for rows rh*16 + q*4 + j.
        // Route to output lane L = row: src quad = (L>>2)&3, reg = L&3.
        const int srcl = ((lane >> 2) & 3) * 16;
        const float s0v = __shfl(p0, srcl, 64);
        const float s1v = __shfl(p1, srcl, 64);
        const float s2v = __shfl(p2, srcl, 64);
        const float s3v = __shfl(p3, srcl, 64);
        const float sA  = (lane & 1) ? s1v : s0v;
        const float sB  = (lane & 1) ? s3v : s2v;
        const float ps  = (lane & 2) ? sB : sA;
        if (rh == 0) pr0 = ps; else pr1 = ps;
    }

    // ---------- outputs (lanes 0..31) ----------
    if (lane < WROWS) {
        const int   r     = rbase + lane;
        const int   b     = r >> 11;
        const int   n     = r & (N_SZ - 1);
        const float p     = ((lane < 16) ? pr0 : pr1) + b2v;
        const float pxx   = fabsf(p) * ex;
        const float x_new = ex - pxx;
        float* ob = out_ + (size_t)b * (5 * N_SZ) + n;
        ob[0 * N_SZ] = x_new;
        ob[1 * N_SZ] = x_new - elb;               // has_lb all-true
        ob[2 * N_SZ] = eub - x_new;               // has_ub all-true
        ob[3 * N_SZ] = ez1 - eD1 * (ez1 - pxx);
        ob[4 * N_SZ] = ez2 - eD2 * (ez2 + pxx);
    }
}

extern "C" void kernel_launch(void* const* d_in, const int* in_sizes, int n_in,
                              void* d_out, int out_size, void* d_ws, size_t ws_size,
                              hipStream_t stream) {
    (void)in_sizes; (void)n_in; (void)out_size; (void)d_ws; (void)ws_size;
    const float* x_   = (const float*)d_in[0];
    const float* x1_  = (const float*)d_in[1];
    const float* x2_  = (const float*)d_in[2];
    const float* z1_  = (const float*)d_in[3];
    const float* z2_  = (const float*)d_in[4];
    const float* x1E_ = (const float*)d_in[5];
    const float* x2E_ = (const float*)d_in[6];
    const float* z1E_ = (const float*)d_in[7];
    const float* z2E_ = (const float*)d_in[8];
    const float* muB_ = (const float*)d_in[9];
    const float* lb_  = (const float*)d_in[10];
    const float* ub_  = (const float*)d_in[11];
    const float* Wih_ = (const float*)d_in[14];
    const float* bih_ = (const float*)d_in[16];
    const float* bhh_ = (const float*)d_in[17];
    const float* W1_  = (const float*)d_in[18];
    const float* b1_  = (const float*)d_in[19];
    const float* W2_  = (const float*)d_in[20];
    const float* b2_  = (const float*)d_in[21];
    float* out_ = (float*)d_out;

    ps_lstm_r14<<<NBLK, BLOCKT, 0, stream>>>(
        x_, x1_, x2_, z1_, z2_, x1E_, x2E_, z1E_, z2E_, muB_, lb_, ub_,
        Wih_, bih_, bhh_, W1_, b1_, W2_, b2_, out_);
}

// Round 3
// 134.490 us; speedup vs baseline: 1.1427x; 1.1427x over previous
//
#include <hip/hip_runtime.h>

// PS_L20_LSTM — r15: dual-stream ILP. r14 post-mortem: forcing 2 blocks/CU
// (64-reg budget) caused ~135 MB of scratch spills (FETCH 6->55 MB, WRITE
// 5->87 MB) — true reg demand ~88. With 16-wave blocks occupancy is stuck at
// 1 block/CU for any reg count in (64,128], so regs up to 128 are FREE.
// r13/r14 waves were ~90% latency-stalled (issue work ~5K cyc/wave vs ~55K
// observed). Fix: fuse the two 16-row half-passes into two independent
// register streams (A=rows 0-15, B=rows 16-31) interleaved instruction by
// instruction: each gate A-frag and head B-frag LDS read feeds BOTH streams
// (halves ds_read per MFMA), and every MFMA/trans/VALU chain has a sibling
// to overlap with. No launch_bounds force; barriers/staging unchanged.

typedef _Float16 half8v  __attribute__((ext_vector_type(8)));
typedef _Float16 half4v  __attribute__((ext_vector_type(4)));
typedef float    float4v __attribute__((ext_vector_type(4)));

#define N_SZ   2048
#define BLOCKT 1024
#define NWAVES 16
#define NBLK   512          // 512 blk x 16 waves x 32 rows = 262144
#define WROWS  32

__device__ __forceinline__ float fast_rcp(float x) { return __builtin_amdgcn_rcpf(x); }
__device__ __forceinline__ float fast_exp2(float x) {
#if __has_builtin(__builtin_amdgcn_exp2f)
    return __builtin_amdgcn_exp2f(x);
#else
    return exp2f(x);
#endif
}

// Gate pre-activations arrive log2-scaled from the staged weights:
//   di = -log2e*i  -> u = 2^di        = e^-i
//   dg = 2log2e*g  -> v = 2^min(dg,C) = e^2g   (clamp: keep v-1 finite)
//   dv = -log2e*o  -> w = 2^min(dv,C) = e^-o   (clamp: keep 1+w finite)
// c = sigmoid(i)*tanh(g) = (v-1)/((1+u)(1+v));  h = sigmoid(o)*tanh(c).
// One rcp: r = 1/((1+u)(1+v)(1+w)); nm=(v-1)*r; c=nm*(1+w); h=nm*P(c^2).
// If any factor overflows to inf: r->0 -> nm->0 -> h=0 = correct limit.
__device__ __forceinline__ half4v act4(float4v di, float4v dg, float4v dv) {
    half4v h;
    #pragma unroll
    for (int j = 0; j < 4; ++j) {
        const float u  = fast_exp2(di[j]);
        const float v  = fast_exp2(fminf(dg[j], 115.0f));
        const float w  = fast_exp2(fminf(dv[j], 115.0f));
        const float a3 = 1.0f + w;
        const float r  = fast_rcp((1.0f + u) * (1.0f + v) * a3);
        const float nm = (v - 1.0f) * r;
        const float cv = nm * a3;
        const float t  = cv * cv;
        const float P  = __builtin_fmaf(t, __builtin_fmaf(t, __builtin_fmaf(t,
                         -0.02714f, 0.12052f), -0.33157f), 0.99986f);
        h[j] = (_Float16)(nm * P);
    }
    return h;
}

__global__ __launch_bounds__(BLOCKT)
void ps_lstm_r15(const float* __restrict__ x_,
                 const float* __restrict__ x1_,
                 const float* __restrict__ x2_,
                 const float* __restrict__ z1_,
                 const float* __restrict__ z2_,
                 const float* __restrict__ x1E_,
                 const float* __restrict__ x2E_,
                 const float* __restrict__ z1E_,
                 const float* __restrict__ z2E_,
                 const float* __restrict__ muB_,
                 const float* __restrict__ lb_,
                 const float* __restrict__ ub_,
                 const float* __restrict__ Wih_,   // [512][15]
                 const float* __restrict__ bih_,   // [512]
                 const float* __restrict__ bhh_,   // [512]
                 const float* __restrict__ W1_,    // [128][128]
                 const float* __restrict__ b1_,    // [128]
                 const float* __restrict__ W2_,    // [128]
                 const float* __restrict__ b2_,    // [1]
                 float* __restrict__ out_)         // [128][5*2048]
{
    // fragWih[g][kk][lane]: A[m=kk*16+(l&15)][k=(l>>4)*4+j], k==15 = fused bias,
    // pre-scaled by gate's log2 factor.                       6144 h = 12 KiB
    __shared__ __align__(16) _Float16 fragWih[3 * 8 * 64 * 4];
    // fragW1[nt][t][lane]: half8 B-frag for 16x16x32; element j holds
    // W1[n2=nt*16+(l&15)][k], k = 32t + (j<4 ? (l>>4)*4+j : 16+(l>>4)*4+j-4)
    // -- the exact neuron order the gate D-frags deliver.    16384 h = 32 KiB
    __shared__ __align__(16) _Float16 fragW1 [8 * 4 * 64 * 8];
    __shared__ __align__(16) _Float16 sFeat[NWAVES][WROWS * 16]; // 16 KiB
    __shared__ __align__(8)  float    sHead[2 * 128];  // (b1,W2) pairs, 1 KiB
    // total ~61 KiB -> LDS would fit 2 blocks; regs (~110) give 1 block/CU

    const int tid  = threadIdx.x;
    const int lane = tid & 63;
    const int w    = tid >> 6;
    const int c    = lane & 15;    // MFMA lane index
    const int q    = lane >> 4;    // quad

    // ---------- one-time staging ----------
    // gate weights, log2-domain pre-scale folded in (i,g,o; dead f skipped)
    for (int ch = tid; ch < 3 * 8 * 64; ch += BLOCKT) {      // 2 iters
        const int g   = ch >> 9;            // 0:i 1:g 2:o
        const int rem = ch & 511;
        const int kk  = rem >> 6;
        const int l   = rem & 63;
        const int m   = kk * 16 + (l & 15);
        const int q4  = l >> 4;
        const int grow = (g == 0 ? m : (g == 1 ? 256 + m : 384 + m));
        const float gs = (g == 1) ? 2.8853901f : -1.4426950f;  // ±log2e, 2log2e
        half4v hh;
        #pragma unroll
        for (int j = 0; j < 4; ++j) {
            const int k = q4 * 4 + j;
            const float raw = (k < 15) ? Wih_[grow * 15 + k]
                                       : (bih_[grow] + bhh_[grow]);
            hh[j] = (_Float16)(gs * raw);
        }
        *(half4v*)&fragWih[(size_t)ch * 4] = hh;
    }
    // W1^T frags in the paired-slice neuron order (j<4: slice 2t, j>=4: 2t+1)
    for (int ch = tid; ch < 8 * 4 * 64; ch += BLOCKT) {      // 2 iters
        const int nt = ch >> 8;
        const int t  = (ch >> 6) & 3;
        const int l  = ch & 63;
        const int n2 = nt * 16 + (l & 15);
        const int q4 = l >> 4;
        const int k0 = 32 * t + q4 * 4;          // j = 0..3
        const int k1 = k0 + 16;                  // j = 4..7
        const float4 a = *(const float4*)&W1_[n2 * 128 + k0];
        const float4 b = *(const float4*)&W1_[n2 * 128 + k1];
        half8v hh;
        hh[0] = (_Float16)a.x; hh[1] = (_Float16)a.y;
        hh[2] = (_Float16)a.z; hh[3] = (_Float16)a.w;
        hh[4] = (_Float16)b.x; hh[5] = (_Float16)b.y;
        hh[6] = (_Float16)b.z; hh[7] = (_Float16)b.w;
        *(half8v*)&fragW1[(size_t)ch * 8] = hh;
    }
    // head bias/weight pairs -> LDS
    if (tid < 128) {
        sHead[2 * tid]     = b1_[tid];
        sHead[2 * tid + 1] = W2_[tid];
    }
    const float b2v = b2_[0];   // uniform -> SGPR

    __syncthreads();   // the only barrier

    const int rbase = (blockIdx.x * NWAVES + w) * WROWS;

    // ---------- stage 1: features (lanes 0..31, lane = row) ----------
    float ex = 0.f, ez1 = 0.f, ez2 = 0.f, eD1 = 0.f, eD2 = 0.f, elb = 0.f, eub = 0.f;
    if (lane < WROWS) {
        const int r = rbase + lane;
        const float x   = x_[r];
        const float x1  = x1_[r];
        const float x2  = x2_[r];
        float       z1  = z1_[r];
        float       z2  = z2_[r];
        const float x1E = x1E_[r];
        const float x2E = x2E_[r];
        const float z1E = z1E_[r];
        const float z2E = z2E_[r];
        const float mu  = muB_[r >> 11];

        z1 = ((z1 + mu) <= 0.0f) ? 0.0f : z1;
        z2 = ((z2 + mu) <= 0.0f) ? 0.0f : z2;
        float invD1 = (z1 + mu) * fast_rcp(x1 + mu + 1e-12f);
        float invD2 = (z2 + mu) * fast_rcp(x2 + mu + 1e-12f);
        invD1 = fminf(fmaxf(invD1, 0.0f), 100.0f);
        invD2 = fminf(fmaxf(invD2, 0.0f), 100.0f);

        const float f[15] = { x, x1, x2, z1, z2, x, z1, z2,
                              x1E, x2E, z1E, z2E, mu, invD1, invD2 };
        half8v f0, f1;
        #pragma unroll
        for (int k = 0; k < 8; ++k) f0[k] = (_Float16)f[k];
        #pragma unroll
        for (int k = 0; k < 7; ++k) f1[k] = (_Float16)f[8 + k];
        f1[7] = (_Float16)1.0f;                 // bias activator (k=15)
        *(half8v*)&sFeat[w][lane * 16]     = f0;
        *(half8v*)&sFeat[w][lane * 16 + 8] = f1;

        ex = x; ez1 = z1; ez2 = z2; eD1 = invD1; eD2 = invD2;
        elb = lb_[r]; eub = ub_[r];
    }
    // wave-private LDS; same-wave DS ordering -> no barrier

    // ---------- fused dual-stream pass (A = rows 0-15, B = rows 16-31) ----------
    // feat B-frags: B[k=q*4+j][n=row c]
    const half4v fB0 = *(const half4v*)&sFeat[w][(c)      * 16 + q * 4];
    const half4v fB1 = *(const half4v*)&sFeat[w][(16 + c) * 16 + q * 4];

    // gate phase: 128 h-values per stream -> 8x half8 regs (32 VGPR total)
    half8v h0a, h1a, h2a, h3a, h0b, h1b, h2b, h3b;
#define GSTEP2(T, HA, HB) { \
    const _Float16* wp = fragWih + lane * 4 + (T) * 512; \
    const float4v zc = {0.f, 0.f, 0.f, 0.f}; \
    const half4v Ai0 = *(const half4v*)(wp); \
    const half4v Ag0 = *(const half4v*)(wp + 2048); \
    const half4v Ao0 = *(const half4v*)(wp + 4096); \
    const float4v diA0 = __builtin_amdgcn_mfma_f32_16x16x16f16(Ai0, fB0, zc, 0, 0, 0); \
    const float4v diB0 = __builtin_amdgcn_mfma_f32_16x16x16f16(Ai0, fB1, zc, 0, 0, 0); \
    const float4v dgA0 = __builtin_amdgcn_mfma_f32_16x16x16f16(Ag0, fB0, zc, 0, 0, 0); \
    const float4v dgB0 = __builtin_amdgcn_mfma_f32_16x16x16f16(Ag0, fB1, zc, 0, 0, 0); \
    const float4v dvA0 = __builtin_amdgcn_mfma_f32_16x16x16f16(Ao0, fB0, zc, 0, 0, 0); \
    const float4v dvB0 = __builtin_amdgcn_mfma_f32_16x16x16f16(Ao0, fB1, zc, 0, 0, 0); \
    const half4v hLoA = act4(diA0, dgA0, dvA0); \
    const half4v hLoB = act4(diB0, dgB0, dvB0); \
    const half4v Ai1 = *(const half4v*)(wp + 256); \
    const half4v Ag1 = *(const half4v*)(wp + 2048 + 256); \
    const half4v Ao1 = *(const half4v*)(wp + 4096 + 256); \
    const float4v diA1 = __builtin_amdgcn_mfma_f32_16x16x16f16(Ai1, fB0, zc, 0, 0, 0); \
    const float4v diB1 = __builtin_amdgcn_mfma_f32_16x16x16f16(Ai1, fB1, zc, 0, 0, 0); \
    const float4v dgA1 = __builtin_amdgcn_mfma_f32_16x16x16f16(Ag1, fB0, zc, 0, 0, 0); \
    const float4v dgB1 = __builtin_amdgcn_mfma_f32_16x16x16f16(Ag1, fB1, zc, 0, 0, 0); \
    const float4v dvA1 = __builtin_amdgcn_mfma_f32_16x16x16f16(Ao1, fB0, zc, 0, 0, 0); \
    const float4v dvB1 = __builtin_amdgcn_mfma_f32_16x16x16f16(Ao1, fB1, zc, 0, 0, 0); \
    const half4v hHiA = act4(diA1, dgA1, dvA1); \
    const half4v hHiB = act4(diB1, dgB1, dvB1); \
    HA[0] = hLoA[0]; HA[1] = hLoA[1]; HA[2] = hLoA[2]; HA[3] = hLoA[3]; \
    HA[4] = hHiA[0]; HA[5] = hHiA[1]; HA[6] = hHiA[2]; HA[7] = hHiA[3]; \
    HB[0] = hLoB[0]; HB[1] = hLoB[1]; HB[2] = hLoB[2]; HB[3] = hLoB[3]; \
    HB[4] = hHiB[0]; HB[5] = hHiB[1]; HB[6] = hHiB[2]; HB[7] = hHiB[3]; }
    GSTEP2(0, h0a, h0b)  GSTEP2(1, h1a, h1b)
    GSTEP2(2, h2a, h2b)  GSTEP2(3, h3a, h3b)
#undef GSTEP2

    // head phase: one 4-reg acc per stream; Bw frags shared by both streams
    float p0a = 0.f, p1a = 0.f, p2a = 0.f, p3a = 0.f;
    float p0b = 0.f, p1b = 0.f, p2b = 0.f, p3b = 0.f;
    #pragma unroll 1
    for (int nt = 0; nt < 8; ++nt) {
        const _Float16* w1p = fragW1 + lane * 8 + nt * 2048;
        const float4v zc = {0.f, 0.f, 0.f, 0.f};
        const half8v Bw0 = *(const half8v*)(w1p       );
        const half8v Bw1 = *(const half8v*)(w1p +  512);
        const half8v Bw2 = *(const half8v*)(w1p + 1024);
        const half8v Bw3 = *(const half8v*)(w1p + 1536);
        float4v accA, accB;
        accA = __builtin_amdgcn_mfma_f32_16x16x32_f16(h0a, Bw0, zc,   0, 0, 0);
        accB = __builtin_amdgcn_mfma_f32_16x16x32_f16(h0b, Bw0, zc,   0, 0, 0);
        accA = __builtin_amdgcn_mfma_f32_16x16x32_f16(h1a, Bw1, accA, 0, 0, 0);
        accB = __builtin_amdgcn_mfma_f32_16x16x32_f16(h1b, Bw1, accB, 0, 0, 0);
        accA = __builtin_amdgcn_mfma_f32_16x16x32_f16(h2a, Bw2, accA, 0, 0, 0);
        accB = __builtin_amdgcn_mfma_f32_16x16x32_f16(h2b, Bw2, accB, 0, 0, 0);
        accA = __builtin_amdgcn_mfma_f32_16x16x32_f16(h3a, Bw3, accA, 0, 0, 0);
        accB = __builtin_amdgcn_mfma_f32_16x16x32_f16(h3b, Bw3, accB, 0, 0, 0);
        const float2 bw = *(const float2*)(sHead + 2 * c + nt * 32);
        p0a = __builtin_fmaf(fmaxf(accA[0] + bw.x, 0.f), bw.y, p0a);
        p1a = __builtin_fmaf(fmaxf(accA[1] + bw.x, 0.f), bw.y, p1a);
        p2a = __builtin_fmaf(fmaxf(accA[2] + bw.x, 0.f), bw.y, p2a);
        p3a = __builtin_fmaf(fmaxf(accA[3] + bw.x, 0.f), bw.y, p3a);
        p0b = __builtin_fmaf(fmaxf(accB[0] + bw.x, 0.f), bw.y, p0b);
        p1b = __builtin_fmaf(fmaxf(accB[1] + bw.x, 0.f), bw.y, p1b);
        p2b = __builtin_fmaf(fmaxf(accB[2] + bw.x, 0.f), bw.y, p2b);
        p3b = __builtin_fmaf(fmaxf(accB[3] + bw.x, 0.f), bw.y, p3b);
    }

    // ----- reduce over c-lanes -> p per row (both streams), route -----
    #pragma unroll
    for (int s = 1; s <= 8; s <<= 1) {
        p0a += __shfl_xor(p0a, s, 64);
        p1a += __shfl_xor(p1a, s, 64);
        p2a += __shfl_xor(p2a, s, 64);
        p3a += __shfl_xor(p3a, s, 64);
        p0b += __shfl_xor(p0b, s, 64);
        p1b += __shfl_xor(p1b, s, 64);
        p2b += __shfl_xor(p2b, s, 64);
        p3b += __shfl_xor(p3b, s, 64);
    }
    // 16 c-lanes of quad q hold p_j for row (stream base) + q*4 + j.
    // Route to output lane L = row: src quad = (L>>2)&3, reg = L&3.
    const int srcl = ((lane >> 2) & 3) * 16;
    const float s0a = __shfl(p0a, srcl, 64);
    const float s1a = __shfl(p1a, srcl, 64);
    const float s2a = __shfl(p2a, srcl, 64);
    const float s3a = __shfl(p3a, srcl, 64);
    const float sAa = (lane & 1) ? s1a : s0a;
    const float sBa = (lane & 1) ? s3a : s2a;
    const float pr0 = (lane & 2) ? sBa : sAa;     // stream A: rows 0-15
    const float s0b = __shfl(p0b, srcl, 64);
    const float s1b = __shfl(p1b, srcl, 64);
    const float s2b = __shfl(p2b, srcl, 64);
    const float s3b = __shfl(p3b, srcl, 64);
    const float sAb = (lane & 1) ? s1b : s0b;
    const float sBb = (lane & 1) ? s3b : s2b;
    const float pr1 = (lane & 2) ? sBb : sAb;     // stream B: rows 16-31

    // ---------- outputs (lanes 0..31) ----------
    if (lane < WROWS) {
        const int   r     = rbase + lane;
        const int   b     = r >> 11;
        const int   n     = r & (N_SZ - 1);
        const float p     = ((lane < 16) ? pr0 : pr1) + b2v;
        const float pxx   = fabsf(p) * ex;
        const float x_new = ex - pxx;
        float* ob = out_ + (size_t)b * (5 * N_SZ) + n;
        ob[0 * N_SZ] = x_new;
        ob[1 * N_SZ] = x_new - elb;               // has_lb all-true
        ob[2 * N_SZ] = eub - x_new;               // has_ub all-true
        ob[3 * N_SZ] = ez1 - eD1 * (ez1 - pxx);
        ob[4 * N_SZ] = ez2 - eD2 * (ez2 + pxx);
    }
}

extern "C" void kernel_launch(void* const* d_in, const int* in_sizes, int n_in,
                              void* d_out, int out_size, void* d_ws, size_t ws_size,
                              hipStream_t stream) {
    (void)in_sizes; (void)n_in; (void)out_size; (void)d_ws; (void)ws_size;
    const float* x_   = (const float*)d_in[0];
    const float* x1_  = (const float*)d_in[1];
    const float* x2_  = (const float*)d_in[2];
    const float* z1_  = (const float*)d_in[3];
    const float* z2_  = (const float*)d_in[4];
    const float* x1E_ = (const float*)d_in[5];
    const float* x2E_ = (const float*)d_in[6];
    const float* z1E_ = (const float*)d_in[7];
    const float* z2E_ = (const float*)d_in[8];
    const float* muB_ = (const float*)d_in[9];
    const float* lb_  = (const float*)d_in[10];
    const float* ub_  = (const float*)d_in[11];
    const float* Wih_ = (const float*)d_in[14];
    const float* bih_ = (const float*)d_in[16];
    const float* bhh_ = (const float*)d_in[17];
    const float* W1_  = (const float*)d_in[18];
    const float* b1_  = (const float*)d_in[19];
    const float* W2_  = (const float*)d_in[20];
    const float* b2_  = (const float*)d_in[21];
    float* out_ = (float*)d_out;

    ps_lstm_r15<<<NBLK, BLOCKT, 0, stream>>>(
        x_, x1_, x2_, z1_, z2_, x1E_, x2E_, z1E_, z2E_, muB_, lb_, ub_,
        Wih_, bih_, bhh_, W1_, b1_, W2_, b2_, out_);
}